// Round 14
// baseline (7830.408 us; speedup 1.0000x reference)
//
#include <hip/hip_runtime.h>

#define B_ 16
#define C_ 64
#define H_ 128
#define W_ 256
#define K_ 9
#define KDIM_ (K_*C_)            // 576

typedef __attribute__((ext_vector_type(8))) short short8_t;
typedef __attribute__((ext_vector_type(4))) float f32x4;

static __device__ __forceinline__ float bf2f(unsigned short u) {
  union { unsigned int i; float f; } v; v.i = ((unsigned int)u) << 16; return v.f;
}
static __device__ __forceinline__ unsigned short f2bf(float f) {
  union { float f; unsigned int i; } v; v.f = f;
  unsigned int r = v.i + 0x7FFF + ((v.i >> 16) & 1);   // RNE
  return (unsigned short)(r >> 16);
}

// async global->LDS, 16B per lane; lds base wave-uniform, lanes fill +lane*16
static __device__ __forceinline__ void gload_lds16(const void* g, void* l) {
  __builtin_amdgcn_global_load_lds(
      (const __attribute__((address_space(1))) unsigned int*)g,
      (__attribute__((address_space(3))) unsigned int*)l, 16, 0, 0);
}

// All 4 weight tensors [co][ci][kk] fp32 -> A2 chunk layout (16B chunk = 8
// consecutive k for one co): A2[((k>>3)*64+co)*8 + (k&7)], k = kk*64+ci.
__global__ __launch_bounds__(256) void prep_w_all(const float* __restrict__ w0,
                                                  const float* __restrict__ w1,
                                                  const float* __restrict__ w2,
                                                  const float* __restrict__ w3,
                                                  unsigned short* __restrict__ A2) {
  int idx = blockIdx.x * 256 + threadIdx.x;
  if (idx >= C_ * KDIM_) return;
  int which = blockIdx.y;
  const float* w = (which == 0) ? w0 : (which == 1) ? w1 : (which == 2) ? w2 : w3;
  unsigned short* out = A2 + (size_t)which * (C_ * KDIM_);
  int co = idx / KDIM_, k = idx % KDIM_;
  int ci = k & 63, kk = k >> 6;
  out[((size_t)(k >> 3) * 64 + co) * 8 + (k & 7)] =
      f2bf(w[((size_t)co * C_ + ci) * K_ + kk]);
}

// fp32 NCHW -> bf16 ci-minor [b][h][w][ci]
__global__ __launch_bounds__(256) void transpose_in(const float* __restrict__ x,
                                                    unsigned short* __restrict__ Xt) {
  __shared__ float tile[64][65];
  const int w0 = blockIdx.x * 64, h = blockIdx.y, b = blockIdx.z;
  const int t = threadIdx.x;
#pragma unroll
  for (int rep = 0; rep < 16; ++rep) {
    int idx = rep * 256 + t;
    int ci = idx >> 6, wl = idx & 63;
    tile[ci][wl] = x[((size_t)(b * C_ + ci) * H_ + h) * W_ + w0 + wl];
  }
  __syncthreads();
#pragma unroll
  for (int rep = 0; rep < 8; ++rep) {
    int idx = rep * 256 + t;
    int wl = idx >> 5, cp = idx & 31;
    unsigned v = (unsigned)f2bf(tile[cp*2][wl]) | ((unsigned)f2bf(tile[cp*2+1][wl]) << 16);
    *(unsigned*)(Xt + ((size_t)(b * H_ + h) * W_ + w0 + wl) * C_ + cp * 2) = v;
  }
}

// [b][h][w][ci] bf16 -> fp32 NCHW (final output) — proven R4-R6 version
__global__ __launch_bounds__(256) void transpose_out(const unsigned short* __restrict__ F,
                                                     float* __restrict__ out) {
  __shared__ float tile[64][65];
  const int w0 = blockIdx.x * 64, h = blockIdx.y, b = blockIdx.z;
  const int t = threadIdx.x;
#pragma unroll
  for (int rep = 0; rep < 8; ++rep) {
    int idx = rep * 256 + t;
    int wl = idx >> 5, cp = idx & 31;
    unsigned v = *(const unsigned*)(F + ((size_t)(b * H_ + h) * W_ + w0 + wl) * C_ + cp * 2);
    tile[cp*2][wl]   = bf2f((unsigned short)v);
    tile[cp*2+1][wl] = bf2f((unsigned short)(v >> 16));
  }
  __syncthreads();
#pragma unroll
  for (int rep = 0; rep < 16; ++rep) {
    int idx = rep * 256 + t;
    int ci = idx >> 6, wl = idx & 63;
    out[((size_t)(b * C_ + ci) * H_ + h) * W_ + w0 + wl] = tile[ci][wl];
  }
}

// ===== fusedL: decoupled-lookback fused conv+relu-scan on [b][P][Q][ci] =====
// relu-scan is a (max,+) scan: y_p(s) = max(a_p, b_p+s); a_p = max(0,c_p+a_{p-1}),
// b_p = c_p + b_{p-1}. Block = 1 wave = 8 P-rows x 16 Q x 16 co. Grid
// (QLEN/16, B, NSEG*4) with seg = z>>2 SLOWEST -> dispatch-order progress.
// Conv: R12-proven addressing (areg 72 VGPR, 4-slot ring, chunk-XOR swizzle,
// counted vmcnt 6/3/0). After conv: publish local (a7,b7) via agent-scope
// atomics + release flag; lookback-compose all predecessors (already
// published); fixup y_i = max(a_i, b_i + s); store. Seg0 scans directly.
template<int PLEN, int QLEN, int REV, int TRANS>
__global__ __launch_bounds__(64, 2) void fusedL(const unsigned short* __restrict__ X,
                                                unsigned short* __restrict__ Y,
                                                const unsigned short* __restrict__ A2,
                                                const float* __restrict__ bias,
                                                const unsigned short* __restrict__ ZP,
                                                unsigned* __restrict__ pay,
                                                unsigned* __restrict__ flags) {
  __shared__ __align__(16) char ring[4 * 3072];
  const int lane = threadIdx.x;
  const int llo = lane & 15, lhi = lane >> 4;
  const int strip = blockIdx.x, b = blockIdx.y;
  const int seg = blockIdx.z >> 2, cs = blockIdx.z & 3;
  constexpr int NSEG   = PLEN / 8;
  constexpr int STRIPS = QLEN / 16;
  const int q0 = strip * 16;
  const int chain = (b * STRIPS + strip) * 4 + cs;
  const int bid = chain * NSEG + seg;

  // ---- A slice -> registers ----
  short8_t areg[18];
#pragma unroll
  for (int st = 0; st < 18; ++st)
    areg[st] = *(const short8_t*)(A2 + (size_t)((st*4 + lhi)*64 + cs*16 + llo) * 8);
  const float4 bv = *(const float4*)(bias + cs*16 + lhi*4);

  auto stageRow = [&](int il) {              // il = local row 0..7
    const int ig = seg * 8 + il;
    const int p = REV ? (PLEN - 1 - ig) : ig;
    char* dst = ring + (il & 3) * 3072;
    const int rr = lane >> 3, sl = lane & 7;
#pragma unroll
    for (int g = 0; g < 3; ++g) {
      int r = g*8 + rr;
      int chunk = sl ^ (r & 7);
      int sq = q0 - 4 + r;
      const void* src = ((unsigned)sq < (unsigned)QLEN)
        ? (const void*)(X + ((size_t)(b*PLEN + p)*QLEN + sq)*64 + chunk*8)
        : (const void*)(ZP + sl*8);
      gload_lds16(src, dst + g*1024);
    }
  };

  auto convRow = [&](int il) -> f32x4 {
    const char* sp = ring + (il & 3) * 3072;
    f32x4 acc = {0.f,0.f,0.f,0.f};
#pragma unroll
    for (int st = 0; st < 18; ++st) {
      int r = llo + (st >> 1);
      int cg = (st & 1)*4 + lhi;
      short8_t f = *(const short8_t*)(sp + r*128 + ((cg ^ (r & 7)) << 4));
      acc = __builtin_amdgcn_mfma_f32_16x16x32_bf16(areg[st], f, acc, 0, 0, 0);
    }
    return acc;
  };

  auto storeRow = [&](int il, uint2 v) {
    const int ig = seg * 8 + il;
    const int p = REV ? (PLEN - 1 - ig) : ig;
    const int q = q0 + llo;
    size_t off = TRANS ? (((size_t)(b*QLEN + q)*PLEN + p)*64)
                       : (((size_t)(b*PLEN + p)*QLEN + q)*64);
    *(uint2*)(Y + off + cs*16 + lhi*4) = v;
  };

  auto pack = [&](float v0, float v1, float v2, float v3) -> uint2 {
    unsigned lo, hi;
    asm("v_cvt_pk_bf16_f32 %0, %1, %2" : "=v"(lo) : "v"(v0), "v"(v1));
    asm("v_cvt_pk_bf16_f32 %0, %1, %2" : "=v"(hi) : "v"(v2), "v"(v3));
    uint2 r; r.x = lo; r.y = hi; return r;
  };

  // ---- conv phase: stage 0,1 then rolling depth-2; vmcnt 6/6.../3/0 ----
  stageRow(0); stageRow(1);

  uint2 ypk[8];
  f32x4 bs[8];
  float A0, A1, A2r, A3, Bb0, Bb1, Bb2, Bb3;   // running (a,b) / (y) state

  if (seg == 0) {
    float y0, y1, y2, y3;
#pragma unroll
    for (int i = 0; i < 8; ++i) {
      if (i + 2 < 8) { stageRow(i + 2); asm volatile("s_waitcnt vmcnt(6)" ::: "memory"); }
      else if (i == 6) { asm volatile("s_waitcnt vmcnt(3)" ::: "memory"); }
      else             { asm volatile("s_waitcnt vmcnt(0)" ::: "memory"); }
      if (i == 0) {
        const int r0 = llo + 4;
        const int cc = cs*2 + (lhi >> 1);
        uint2 v = *(const uint2*)(ring + r0*128 + ((cc ^ (r0 & 7)) << 4) + (lhi & 1)*8);
        y0 = bf2f((unsigned short)v.x); y1 = bf2f((unsigned short)(v.x >> 16));
        y2 = bf2f((unsigned short)v.y); y3 = bf2f((unsigned short)(v.y >> 16));
        ypk[0] = v;                           // boundary row copied bit-exact
      } else {
        f32x4 c = convRow(i);
        y0 = fmaxf(c[0] + bv.x + y0, 0.f);
        y1 = fmaxf(c[1] + bv.y + y1, 0.f);
        y2 = fmaxf(c[2] + bv.z + y2, 0.f);
        y3 = fmaxf(c[3] + bv.w + y3, 0.f);
        ypk[i] = pack(y0, y1, y2, y3);
      }
    }
    A0 = y0; A1 = y1; A2r = y2; A3 = y3;
    Bb0 = Bb1 = Bb2 = Bb3 = -3.0e38f;
  } else {
    float a0 = -3.0e38f, a1 = -3.0e38f, a2 = -3.0e38f, a3 = -3.0e38f;
    float b0 = 0.f, b1 = 0.f, b2 = 0.f, b3 = 0.f;
#pragma unroll
    for (int i = 0; i < 8; ++i) {
      if (i + 2 < 8) { stageRow(i + 2); asm volatile("s_waitcnt vmcnt(6)" ::: "memory"); }
      else if (i == 6) { asm volatile("s_waitcnt vmcnt(3)" ::: "memory"); }
      else             { asm volatile("s_waitcnt vmcnt(0)" ::: "memory"); }
      f32x4 c = convRow(i);
      float c0 = c[0] + bv.x, c1 = c[1] + bv.y, c2 = c[2] + bv.z, c3 = c[3] + bv.w;
      a0 = fmaxf(c0 + a0, 0.f); a1 = fmaxf(c1 + a1, 0.f);
      a2 = fmaxf(c2 + a2, 0.f); a3 = fmaxf(c3 + a3, 0.f);
      b0 += c0; b1 += c1; b2 += c2; b3 += c3;
      ypk[i] = pack(a0, a1, a2, a3);          // provisional (zero-carry) y
      f32x4 bb = {b0, b1, b2, b3};
      bs[i] = bb;
    }
    A0 = a0; A1 = a1; A2r = a2; A3 = a3;
    Bb0 = b0; Bb1 = b1; Bb2 = b2; Bb3 = b3;
  }

  // ---- publish local segment map (A,B) + release flag ----
  {
    unsigned* pp = pay + (size_t)bid * 512 + lane * 8;
    __hip_atomic_store(pp+0, __float_as_uint(A0),  __ATOMIC_RELAXED, __HIP_MEMORY_SCOPE_AGENT);
    __hip_atomic_store(pp+1, __float_as_uint(A1),  __ATOMIC_RELAXED, __HIP_MEMORY_SCOPE_AGENT);
    __hip_atomic_store(pp+2, __float_as_uint(A2r), __ATOMIC_RELAXED, __HIP_MEMORY_SCOPE_AGENT);
    __hip_atomic_store(pp+3, __float_as_uint(A3),  __ATOMIC_RELAXED, __HIP_MEMORY_SCOPE_AGENT);
    __hip_atomic_store(pp+4, __float_as_uint(Bb0), __ATOMIC_RELAXED, __HIP_MEMORY_SCOPE_AGENT);
    __hip_atomic_store(pp+5, __float_as_uint(Bb1), __ATOMIC_RELAXED, __HIP_MEMORY_SCOPE_AGENT);
    __hip_atomic_store(pp+6, __float_as_uint(Bb2), __ATOMIC_RELAXED, __HIP_MEMORY_SCOPE_AGENT);
    __hip_atomic_store(pp+7, __float_as_uint(Bb3), __ATOMIC_RELAXED, __HIP_MEMORY_SCOPE_AGENT);
    if (lane == 0)
      __hip_atomic_store(flags + bid, 1u, __ATOMIC_RELEASE, __HIP_MEMORY_SCOPE_AGENT);
  }

  if (seg == 0) {
#pragma unroll
    for (int i = 0; i < 8; ++i) storeRow(i, ypk[i]);
    return;
  }

  // ---- lookback: compose predecessors' maps (all published ~now) ----
  float s0 = 0.f, s1 = 0.f, s2 = 0.f, s3 = 0.f;
  for (int j = 0; j < seg; ++j) {
    const int jb = chain * NSEG + j;
    while (__hip_atomic_load(flags + jb, __ATOMIC_ACQUIRE, __HIP_MEMORY_SCOPE_AGENT) == 0u)
      __builtin_amdgcn_s_sleep(2);
    const unsigned* pp = pay + (size_t)jb * 512 + lane * 8;
    float Aj0 = __uint_as_float(__hip_atomic_load(pp+0, __ATOMIC_RELAXED, __HIP_MEMORY_SCOPE_AGENT));
    float Aj1 = __uint_as_float(__hip_atomic_load(pp+1, __ATOMIC_RELAXED, __HIP_MEMORY_SCOPE_AGENT));
    float Aj2 = __uint_as_float(__hip_atomic_load(pp+2, __ATOMIC_RELAXED, __HIP_MEMORY_SCOPE_AGENT));
    float Aj3 = __uint_as_float(__hip_atomic_load(pp+3, __ATOMIC_RELAXED, __HIP_MEMORY_SCOPE_AGENT));
    float Bj0 = __uint_as_float(__hip_atomic_load(pp+4, __ATOMIC_RELAXED, __HIP_MEMORY_SCOPE_AGENT));
    float Bj1 = __uint_as_float(__hip_atomic_load(pp+5, __ATOMIC_RELAXED, __HIP_MEMORY_SCOPE_AGENT));
    float Bj2 = __uint_as_float(__hip_atomic_load(pp+6, __ATOMIC_RELAXED, __HIP_MEMORY_SCOPE_AGENT));
    float Bj3 = __uint_as_float(__hip_atomic_load(pp+7, __ATOMIC_RELAXED, __HIP_MEMORY_SCOPE_AGENT));
    s0 = fmaxf(Aj0, Bj0 + s0); s1 = fmaxf(Aj1, Bj1 + s1);
    s2 = fmaxf(Aj2, Bj2 + s2); s3 = fmaxf(Aj3, Bj3 + s3);
  }

  // ---- fixup + store: y_i = max(a_i, b_i + s) ----
#pragma unroll
  for (int i = 0; i < 8; ++i) {
    float a0 = bf2f((unsigned short)ypk[i].x);
    float a1 = bf2f((unsigned short)(ypk[i].x >> 16));
    float a2 = bf2f((unsigned short)ypk[i].y);
    float a3 = bf2f((unsigned short)(ypk[i].y >> 16));
    float y0 = fmaxf(a0, bs[i][0] + s0);
    float y1 = fmaxf(a1, bs[i][1] + s1);
    float y2 = fmaxf(a2, bs[i][2] + s2);
    float y3 = fmaxf(a3, bs[i][3] + s3);
    storeRow(i, pack(y0, y1, y2, y3));
  }
}

extern "C" void kernel_launch(void* const* d_in, const int* in_sizes, int n_in,
                              void* d_out, int out_size, void* d_ws, size_t ws_size,
                              hipStream_t stream) {
  const float* x    = (const float*)d_in[0];
  const float* w_ud = (const float*)d_in[1];
  const float* b_ud = (const float*)d_in[2];
  const float* w_du = (const float*)d_in[3];
  const float* b_du = (const float*)d_in[4];
  const float* w_lr = (const float*)d_in[5];
  const float* b_lr = (const float*)d_in[6];
  const float* w_rl = (const float*)d_in[7];
  const float* b_rl = (const float*)d_in[8];

  // ws: A[0,64M) Bb[64M,128M) Cc[128M,192M) A2@192M ZP@196M PAY@200M(32M) FLAGS@240M
  unsigned short* A  = (unsigned short*)d_ws;
  unsigned short* Bb = (unsigned short*)((char*)d_ws + 67108864);
  unsigned short* Cc = (unsigned short*)((char*)d_ws + 134217728);
  unsigned short* A2 = (unsigned short*)((char*)d_ws + 201326592);
  unsigned short* ZP = (unsigned short*)((char*)d_ws + 205520896);
  unsigned*       PAY   = (unsigned*)((char*)d_ws + 209715200);
  unsigned*       FLAGS = (unsigned*)((char*)d_ws + 251658240);
  unsigned short* A2_ud = A2 + 0 * (C_ * KDIM_);
  unsigned short* A2_du = A2 + 1 * (C_ * KDIM_);
  unsigned short* A2_lr = A2 + 2 * (C_ * KDIM_);
  unsigned short* A2_rl = A2 + 3 * (C_ * KDIM_);

  hipMemsetAsync(ZP, 0, 1024, stream);
  hipMemsetAsync(FLAGS, 0, 4 * 65536, stream);

  dim3 pg((C_ * KDIM_ + 255) / 256, 4);
  prep_w_all<<<pg, 256, 0, stream>>>(w_ud, w_du, w_lr, w_rl, A2);

  transpose_in<<<dim3(4, H_, B_), 256, 0, stream>>>(x, A);

  // sweep 1 (ud): [b][h][w][ci], conv along w, scan fwd along h
  fusedL<H_, W_, 0, 0><<<dim3(16, B_, (H_/8)*4), 64, 0, stream>>>(
      A,  Bb, A2_ud, b_ud, ZP, PAY, FLAGS + 0*16384);
  // sweep 2 (du): scan rev along h, write TRANSPOSED -> [b][w][h][ci]
  fusedL<H_, W_, 1, 1><<<dim3(16, B_, (H_/8)*4), 64, 0, stream>>>(
      Bb, Cc, A2_du, b_du, ZP, PAY, FLAGS + 1*16384);
  // sweep 3 (lr): flipped layout, conv along h (inner), scan fwd along w (outer)
  fusedL<W_, H_, 0, 0><<<dim3(8, B_, (W_/8)*4), 64, 0, stream>>>(
      Cc, A, A2_lr, b_lr, ZP, PAY, FLAGS + 2*16384);
  // sweep 4 (rl): scan rev along w, write TRANSPOSED -> back to [b][h][w][ci]
  fusedL<W_, H_, 1, 1><<<dim3(8, B_, (W_/8)*4), 64, 0, stream>>>(
      A, Bb, A2_rl, b_rl, ZP, PAY, FLAGS + 3*16384);

  transpose_out<<<dim3(4, H_, B_), 256, 0, stream>>>(Bb, (float*)d_out);
}

// Round 15
// 769.987 us; speedup vs baseline: 10.1695x; 10.1695x over previous
//
#include <hip/hip_runtime.h>

#define B_ 16
#define C_ 64
#define H_ 128
#define W_ 256
#define K_ 9
#define KDIM_ (K_*C_)            // 576

typedef __attribute__((ext_vector_type(8))) short short8_t;
typedef __attribute__((ext_vector_type(4))) float f32x4;

static __device__ __forceinline__ float bf2f(unsigned short u) {
  union { unsigned int i; float f; } v; v.i = ((unsigned int)u) << 16; return v.f;
}
static __device__ __forceinline__ unsigned short f2bf(float f) {
  union { float f; unsigned int i; } v; v.f = f;
  unsigned int r = v.i + 0x7FFF + ((v.i >> 16) & 1);   // RNE
  return (unsigned short)(r >> 16);
}

// async global->LDS, 16B per lane; lds base wave-uniform, lanes fill +lane*16
static __device__ __forceinline__ void gload_lds16(const void* g, void* l) {
  __builtin_amdgcn_global_load_lds(
      (const __attribute__((address_space(1))) unsigned int*)g,
      (__attribute__((address_space(3))) unsigned int*)l, 16, 0, 0);
}

// All 4 weight tensors [co][ci][kk] fp32 -> A2 chunk layout (16B chunk = 8
// consecutive k for one co): A2[((k>>3)*64+co)*8 + (k&7)], k = kk*64+ci.
__global__ __launch_bounds__(256) void prep_w_all(const float* __restrict__ w0,
                                                  const float* __restrict__ w1,
                                                  const float* __restrict__ w2,
                                                  const float* __restrict__ w3,
                                                  unsigned short* __restrict__ A2) {
  int idx = blockIdx.x * 256 + threadIdx.x;
  if (idx >= C_ * KDIM_) return;
  int which = blockIdx.y;
  const float* w = (which == 0) ? w0 : (which == 1) ? w1 : (which == 2) ? w2 : w3;
  unsigned short* out = A2 + (size_t)which * (C_ * KDIM_);
  int co = idx / KDIM_, k = idx % KDIM_;
  int ci = k & 63, kk = k >> 6;
  out[((size_t)(k >> 3) * 64 + co) * 8 + (k & 7)] =
      f2bf(w[((size_t)co * C_ + ci) * K_ + kk]);
}

// fp32 NCHW -> bf16 ci-minor [b][h][w][ci]
__global__ __launch_bounds__(256) void transpose_in(const float* __restrict__ x,
                                                    unsigned short* __restrict__ Xt) {
  __shared__ float tile[64][65];
  const int w0 = blockIdx.x * 64, h = blockIdx.y, b = blockIdx.z;
  const int t = threadIdx.x;
#pragma unroll
  for (int rep = 0; rep < 16; ++rep) {
    int idx = rep * 256 + t;
    int ci = idx >> 6, wl = idx & 63;
    tile[ci][wl] = x[((size_t)(b * C_ + ci) * H_ + h) * W_ + w0 + wl];
  }
  __syncthreads();
#pragma unroll
  for (int rep = 0; rep < 8; ++rep) {
    int idx = rep * 256 + t;
    int wl = idx >> 5, cp = idx & 31;
    unsigned v = (unsigned)f2bf(tile[cp*2][wl]) | ((unsigned)f2bf(tile[cp*2+1][wl]) << 16);
    *(unsigned*)(Xt + ((size_t)(b * H_ + h) * W_ + w0 + wl) * C_ + cp * 2) = v;
  }
}

// ===== conv6: square-tile MFMA conv on [b][R][Q][ci], conv along Q =====
// Grid 256 (1 block/CU, LDS 143KB), 4 waves. Full A (72KB) in LDS; X staged
// as 256-position super-tiles, double-buffered (34KB each, swizzled: LDS slot
// s of row r holds chunk s^(r&7) via pre-swizzled global source).
// QLEN=256: super-tile = 1 row. QLEN=128: super-tile = 2 rows as 2 strips.
// Wave wv owns 64 positions x all 64 co (4x4 MFMA tiles): per K-step
// 4 A ds_reads + 4 X ds_reads feed 16 MFMAs.
template<int QLEN>
__global__ __launch_bounds__(256, 1) void conv6(const unsigned short* __restrict__ X,
                                                unsigned short* __restrict__ Y,
                                                const unsigned short* __restrict__ A2,
                                                const float* __restrict__ bias,
                                                const unsigned short* __restrict__ ZP) {
  constexpr int SEGROWS = 256 / QLEN;              // 1 or 2 strips
  constexpr int NG      = (256 + 8 * SEGROWS) / 8; // 33 or 34 groups of 1KB
  __shared__ __align__(16) char lds[73728 + 2 * 34816];
  char* Alds  = lds;
  char* xbuf0 = lds + 73728;
  char* xbuf1 = lds + 73728 + 34816;

  const int t = threadIdx.x;
  const int lane = t & 63, wv = t >> 6;
  const int llo = lane & 15, lhi = lane >> 4;

  // ---- A -> LDS: 72 x 1KB groups, 18 per wave ----
#pragma unroll
  for (int i = 0; i < 18; ++i) {
    int m = wv + i * 4;
    gload_lds16(A2 + (size_t)m * 512 + lane * 8, Alds + m * 1024);
  }

  // stage super-tile u into dst
  auto stageX = [&](char* dst, int u) {
#pragma unroll
    for (int i = 0; i < 9; ++i) {
      int gl = wv + i * 4;
      if (gl < NG) {
        int strip = (SEGROWS == 2 && gl >= 17) ? 1 : 0;
        int gg = gl - strip * 17;
        int r = gg * 8 + (lane >> 3);            // row within strip
        int slot = lane & 7;
        int chunk = slot ^ (r & 7);
        int q = r - 4;
        int rowId = (SEGROWS == 1) ? u : u * 2 + strip;
        const void* src = ((unsigned)q < (unsigned)QLEN)
            ? (const void*)(X + (size_t)rowId * (QLEN * 64) + (size_t)q * 64 + chunk * 8)
            : (const void*)(ZP + slot * 8);
        gload_lds16(src, dst + strip * 17408 + gg * 1024);
      }
    }
  };

  float4 bv[4];
#pragma unroll
  for (int j = 0; j < 4; ++j) bv[j] = *(const float4*)(bias + j * 16 + lhi * 4);

  const int stripoff = (SEGROWS == 1) ? 0 : (wv >> 1) * 17408;
  const int posbase  = (SEGROWS == 1) ? wv * 64 : (wv & 1) * 64;

  const int u0 = blockIdx.x * 8;
  stageX(xbuf0, u0);
  __syncthreads();

  for (int tt = 0; tt < 8; ++tt) {
    const int u = u0 + tt;
    char* cur = (tt & 1) ? xbuf1 : xbuf0;
    char* nxt = (tt & 1) ? xbuf0 : xbuf1;
    if (tt < 7) stageX(nxt, u + 1);              // issue BEFORE compute

    const char* xb = cur + stripoff;
    f32x4 acc[4][4];
#pragma unroll
    for (int i = 0; i < 4; ++i)
#pragma unroll
      for (int j = 0; j < 4; ++j) { f32x4 z = {0.f,0.f,0.f,0.f}; acc[i][j] = z; }

#pragma unroll
    for (int step = 0; step < 18; ++step) {
      const int kk = step >> 1;
      const int cg = (step & 1) * 4 + lhi;
      short8_t a[4], f[4];
#pragma unroll
      for (int j = 0; j < 4; ++j)
        a[j] = *(const short8_t*)(Alds + step * 4096 + lhi * 1024 + j * 256 + llo * 16);
#pragma unroll
      for (int i = 0; i < 4; ++i) {
        int r = posbase + i * 16 + llo + kk;
        f[i] = *(const short8_t*)(xb + r * 128 + ((cg ^ (r & 7)) << 4));
      }
#pragma unroll
      for (int i = 0; i < 4; ++i)
#pragma unroll
        for (int j = 0; j < 4; ++j)
          acc[i][j] = __builtin_amdgcn_mfma_f32_16x16x32_bf16(a[j], f[i], acc[i][j], 0, 0, 0);
    }

    // epilogue: +bias, pack 4 consecutive co, 8B stores
    const int outRow = (SEGROWS == 1) ? u : u * 2 + (wv >> 1);
    const size_t rowbase = (size_t)outRow * (QLEN * 64);
#pragma unroll
    for (int j = 0; j < 4; ++j) {
#pragma unroll
      for (int i = 0; i < 4; ++i) {
        const int q = posbase + i * 16 + llo;
        float v0 = acc[i][j][0] + bv[j].x;
        float v1 = acc[i][j][1] + bv[j].y;
        float v2 = acc[i][j][2] + bv[j].z;
        float v3 = acc[i][j][3] + bv[j].w;
        unsigned lo, hi;
        asm("v_cvt_pk_bf16_f32 %0, %1, %2" : "=v"(lo) : "v"(v0), "v"(v1));
        asm("v_cvt_pk_bf16_f32 %0, %1, %2" : "=v"(hi) : "v"(v2), "v"(v3));
        uint2 ov; ov.x = lo; ov.y = hi;
        *(uint2*)(Y + rowbase + (size_t)q * 64 + j * 16 + lhi * 4) = ov;
      }
    }
    __syncthreads();
  }
}

// ===== scan along OUTER dim P of [b][P][Q][ci], 4 ci/thread, depth-8 =====
// TRANS=1: write result transposed to [b][Q][P][ci] (outT) instead of in-place.
template<int PLEN, int QLEN, int REV, int TRANS>
__global__ __launch_bounds__(128) void scan_o4(unsigned short* __restrict__ conv,
                                               const unsigned short* __restrict__ prev,
                                               unsigned short* __restrict__ outT) {
  int idx = blockIdx.x * 128 + threadIdx.x;     // B * QLEN * 16
  int cq = idx & 15;
  int q  = (idx >> 4) % QLEN;
  int b  = idx / (16 * QLEN);
  const ptrdiff_t dp = (REV ? -1 : 1) * (ptrdiff_t)(QLEN * 64);
  const int p0 = REV ? PLEN - 1 : 0;
  size_t off = ((size_t)(b * PLEN + p0) * QLEN + q) * 64 + cq * 4;
  size_t offT = 0; ptrdiff_t dpT = 0;
  if (TRANS) {
    offT = ((size_t)(b * QLEN + q) * PLEN + p0) * 64 + cq * 4;
    dpT = (REV ? -1 : 1) * (ptrdiff_t)64;
  }
  uint2 pv = *(const uint2*)(prev + off);
  if (TRANS) *(uint2*)(outT + offT) = pv; else *(uint2*)(conv + off) = pv;
  float y0 = bf2f((unsigned short)pv.x), y1 = bf2f((unsigned short)(pv.x >> 16));
  float y2 = bf2f((unsigned short)pv.y), y3 = bf2f((unsigned short)(pv.y >> 16));
  uint2 c[8];
#pragma unroll
  for (int j = 0; j < 8; ++j) c[j] = *(const uint2*)(conv + off + (ptrdiff_t)(j + 1) * dp);
  for (int base = 1; base < PLEN; base += 8) {
#pragma unroll
    for (int j = 0; j < 8; ++j) {
      int s = base + j;
      if (s < PLEN) {
        off += dp;
        if (TRANS) offT += dpT;
        y0 = fmaxf(bf2f((unsigned short)c[j].x) + y0, 0.f);
        y1 = fmaxf(bf2f((unsigned short)(c[j].x >> 16)) + y1, 0.f);
        y2 = fmaxf(bf2f((unsigned short)c[j].y) + y2, 0.f);
        y3 = fmaxf(bf2f((unsigned short)(c[j].y >> 16)) + y3, 0.f);
        uint2 ov;
        ov.x = (unsigned)f2bf(y0) | ((unsigned)f2bf(y1) << 16);
        ov.y = (unsigned)f2bf(y2) | ((unsigned)f2bf(y3) << 16);
        if (TRANS) *(uint2*)(outT + offT) = ov; else *(uint2*)(conv + off) = ov;
        if (s + 8 < PLEN) c[j] = *(const uint2*)(conv + off + 8 * dp);
      }
    }
  }
}

// ===== scan4_nchw: final sweep's scan on [b][w][h][ci] (P=w, Q=h), writing
// fp32 NCHW output DIRECTLY (replaces scan + transpose_out). Per thread,
// consecutive scan steps = consecutive w -> stride-1 runs per ci-plane;
// L2 write-combines the 4-plane interleave (open lines ~1MB/XCD, fits).
template<int REV>
__global__ __launch_bounds__(128) void scan4_nchw(const unsigned short* __restrict__ conv,
                                                  const unsigned short* __restrict__ prev,
                                                  float* __restrict__ out) {
  int idx = blockIdx.x * 128 + threadIdx.x;     // B * H * 16
  int cq = idx & 15;
  int h  = (idx >> 4) % H_;
  int b  = idx / (16 * H_);
  const ptrdiff_t dp  = (REV ? -1 : 1) * (ptrdiff_t)(H_ * 64);   // conv step (w)
  const ptrdiff_t dpo = (REV ? -1 : 1);                          // out step (w)
  const int p0 = REV ? W_ - 1 : 0;
  size_t off = ((size_t)(b * W_ + p0) * H_ + h) * 64 + cq * 4;
  // out plane base for ci = cq*4 + j : ((b*64 + cq*4 + j)*128 + h)*256 + p
  size_t ob = ((size_t)(b * C_ + cq * 4) * H_ + h) * W_ + p0;
  uint2 pv = *(const uint2*)(prev + off);
  float y0 = bf2f((unsigned short)pv.x), y1 = bf2f((unsigned short)(pv.x >> 16));
  float y2 = bf2f((unsigned short)pv.y), y3 = bf2f((unsigned short)(pv.y >> 16));
  out[ob + 0 * (H_ * W_)] = y0;
  out[ob + 1 * (H_ * W_)] = y1;
  out[ob + 2 * (H_ * W_)] = y2;
  out[ob + 3 * (H_ * W_)] = y3;
  uint2 c[8];
#pragma unroll
  for (int j = 0; j < 8; ++j) c[j] = *(const uint2*)(conv + off + (ptrdiff_t)(j + 1) * dp);
  for (int base = 1; base < W_; base += 8) {
#pragma unroll
    for (int j = 0; j < 8; ++j) {
      int s = base + j;
      if (s < W_) {
        off += dp;
        ob  += dpo;
        y0 = fmaxf(bf2f((unsigned short)c[j].x) + y0, 0.f);
        y1 = fmaxf(bf2f((unsigned short)(c[j].x >> 16)) + y1, 0.f);
        y2 = fmaxf(bf2f((unsigned short)c[j].y) + y2, 0.f);
        y3 = fmaxf(bf2f((unsigned short)(c[j].y >> 16)) + y3, 0.f);
        out[ob + 0 * (H_ * W_)] = y0;
        out[ob + 1 * (H_ * W_)] = y1;
        out[ob + 2 * (H_ * W_)] = y2;
        out[ob + 3 * (H_ * W_)] = y3;
        if (s + 8 < W_) c[j] = *(const uint2*)(conv + off + 8 * dp);
      }
    }
  }
}

extern "C" void kernel_launch(void* const* d_in, const int* in_sizes, int n_in,
                              void* d_out, int out_size, void* d_ws, size_t ws_size,
                              hipStream_t stream) {
  const float* x    = (const float*)d_in[0];
  const float* w_ud = (const float*)d_in[1];
  const float* b_ud = (const float*)d_in[2];
  const float* w_du = (const float*)d_in[3];
  const float* b_du = (const float*)d_in[4];
  const float* w_lr = (const float*)d_in[5];
  const float* b_lr = (const float*)d_in[6];
  const float* w_rl = (const float*)d_in[7];
  const float* b_rl = (const float*)d_in[8];

  // ws: A[0,64M) Bb[64M,128M) Cc[128M,192M) A2 @192M, zeropage @192M+1M
  unsigned short* A  = (unsigned short*)d_ws;
  unsigned short* Bb = (unsigned short*)((char*)d_ws + 67108864);
  unsigned short* Cc = (unsigned short*)((char*)d_ws + 134217728);
  unsigned short* A2 = (unsigned short*)((char*)d_ws + 201326592);
  unsigned short* ZP = (unsigned short*)((char*)d_ws + 202375168);
  unsigned short* A2_ud = A2 + 0 * (C_ * KDIM_);
  unsigned short* A2_du = A2 + 1 * (C_ * KDIM_);
  unsigned short* A2_lr = A2 + 2 * (C_ * KDIM_);
  unsigned short* A2_rl = A2 + 3 * (C_ * KDIM_);

  hipMemsetAsync(ZP, 0, 1024, stream);

  dim3 pg((C_ * KDIM_ + 255) / 256, 4);
  prep_w_all<<<pg, 256, 0, stream>>>(w_ud, w_du, w_lr, w_rl, A2);

  transpose_in<<<dim3(4, H_, B_), 256, 0, stream>>>(x, A);

  // sweep 1 (ud): conv along W on [b][h][w][ci]; scan fwd along h
  conv6<W_><<<256, 256, 0, stream>>>(A, Bb, A2_ud, b_ud, ZP);
  scan_o4<H_, W_, 0, 0><<<512, 128, 0, stream>>>(Bb, A, nullptr);

  // sweep 2 (du): conv along W; scan rev along h, WRITE TRANSPOSED -> [b][w][h][ci]
  conv6<W_><<<256, 256, 0, stream>>>(Bb, Cc, A2_du, b_du, ZP);
  scan_o4<H_, W_, 1, 1><<<512, 128, 0, stream>>>(Cc, Bb, A);

  // sweep 3 (lr): conv along H (inner dim of flipped layout); scan fwd along w
  conv6<H_><<<256, 256, 0, stream>>>(A, Bb, A2_lr, b_lr, ZP);
  scan_o4<W_, H_, 0, 0><<<256, 128, 0, stream>>>(Bb, A, nullptr);

  // sweep 4 (rl): conv along H; scan rev along w, writing fp32 NCHW directly
  conv6<H_><<<256, 256, 0, stream>>>(Bb, Cc, A2_rl, b_rl, ZP);
  scan4_nchw<1><<<256, 128, 0, stream>>>(Cc, Bb, (float*)d_out);
}

// Round 16
// 373.761 us; speedup vs baseline: 20.9503x; 2.0601x over previous
//
#include <hip/hip_runtime.h>

#define B_ 16
#define C_ 64
#define H_ 128
#define W_ 256
#define K_ 9
#define KDIM_ (K_*C_)            // 576

typedef __attribute__((ext_vector_type(8))) short short8_t;
typedef __attribute__((ext_vector_type(4))) float f32x4;

static __device__ __forceinline__ float bf2f(unsigned short u) {
  union { unsigned int i; float f; } v; v.i = ((unsigned int)u) << 16; return v.f;
}
static __device__ __forceinline__ unsigned short f2bf(float f) {
  union { float f; unsigned int i; } v; v.f = f;
  unsigned int r = v.i + 0x7FFF + ((v.i >> 16) & 1);   // RNE
  return (unsigned short)(r >> 16);
}

// async global->LDS, 16B per lane; lds base wave-uniform, lanes fill +lane*16
static __device__ __forceinline__ void gload_lds16(const void* g, void* l) {
  __builtin_amdgcn_global_load_lds(
      (const __attribute__((address_space(1))) unsigned int*)g,
      (__attribute__((address_space(3))) unsigned int*)l, 16, 0, 0);
}

// All 4 weight tensors [co][ci][kk] fp32 -> A2 chunk layout (16B chunk = 8
// consecutive k for one co): A2[((k>>3)*64+co)*8 + (k&7)], k = kk*64+ci.
// ALSO zeroes the 1KB zeropage (replaces a hipMemsetAsync dispatch that cost
// ~75us per replay in the timed graph — R9/R10 rocprof evidence).
__global__ __launch_bounds__(256) void prep_w_all(const float* __restrict__ w0,
                                                  const float* __restrict__ w1,
                                                  const float* __restrict__ w2,
                                                  const float* __restrict__ w3,
                                                  unsigned short* __restrict__ A2,
                                                  float* __restrict__ ZPf) {
  if (blockIdx.y == 0 && blockIdx.x == 0) ZPf[threadIdx.x] = 0.f;  // 1KB zeropage
  int idx = blockIdx.x * 256 + threadIdx.x;
  if (idx >= C_ * KDIM_) return;
  int which = blockIdx.y;
  const float* w = (which == 0) ? w0 : (which == 1) ? w1 : (which == 2) ? w2 : w3;
  unsigned short* out = A2 + (size_t)which * (C_ * KDIM_);
  int co = idx / KDIM_, k = idx % KDIM_;
  int ci = k & 63, kk = k >> 6;
  out[((size_t)(k >> 3) * 64 + co) * 8 + (k & 7)] =
      f2bf(w[((size_t)co * C_ + ci) * K_ + kk]);
}

// fp32 NCHW -> bf16 ci-minor [b][h][w][ci]
__global__ __launch_bounds__(256) void transpose_in(const float* __restrict__ x,
                                                    unsigned short* __restrict__ Xt) {
  __shared__ float tile[64][65];
  const int w0 = blockIdx.x * 64, h = blockIdx.y, b = blockIdx.z;
  const int t = threadIdx.x;
#pragma unroll
  for (int rep = 0; rep < 16; ++rep) {
    int idx = rep * 256 + t;
    int ci = idx >> 6, wl = idx & 63;
    tile[ci][wl] = x[((size_t)(b * C_ + ci) * H_ + h) * W_ + w0 + wl];
  }
  __syncthreads();
#pragma unroll
  for (int rep = 0; rep < 8; ++rep) {
    int idx = rep * 256 + t;
    int wl = idx >> 5, cp = idx & 31;
    unsigned v = (unsigned)f2bf(tile[cp*2][wl]) | ((unsigned)f2bf(tile[cp*2+1][wl]) << 16);
    *(unsigned*)(Xt + ((size_t)(b * H_ + h) * W_ + w0 + wl) * C_ + cp * 2) = v;
  }
}

// [b][w][h][ci] bf16 -> fp32 NCHW (final output, after the layout flip)
__global__ __launch_bounds__(256) void transpose_out_wh(const unsigned short* __restrict__ F,
                                                        float* __restrict__ out) {
  __shared__ float tile[64][65];   // [wl][ci]
  const int w0 = blockIdx.x * 64, h = blockIdx.y, b = blockIdx.z;
  const int t = threadIdx.x;
#pragma unroll
  for (int rep = 0; rep < 4; ++rep) {
    int idx = rep * 256 + t;
    int cp = idx & 15, wl = idx >> 4;
    uint2 v = *(const uint2*)(F + ((size_t)(b * W_ + w0 + wl) * H_ + h) * C_ + cp * 4);
    tile[wl][cp*4+0] = bf2f((unsigned short)v.x);
    tile[wl][cp*4+1] = bf2f((unsigned short)(v.x >> 16));
    tile[wl][cp*4+2] = bf2f((unsigned short)v.y);
    tile[wl][cp*4+3] = bf2f((unsigned short)(v.y >> 16));
  }
  __syncthreads();
#pragma unroll
  for (int rep = 0; rep < 16; ++rep) {
    int idx = rep * 256 + t;
    int ci = idx >> 6, wl = idx & 63;
    out[((size_t)(b * C_ + ci) * H_ + h) * W_ + w0 + wl] = tile[wl][ci];
  }
}

// ===== conv6: square-tile MFMA conv on [b][R][Q][ci], conv along Q =====
// Grid 256 (1 block/CU, LDS 143KB), 4 waves. Full A (72KB) in LDS; X staged
// as 256-position super-tiles, double-buffered (34KB each, swizzled: LDS slot
// s of row r holds chunk s^(r&7) via pre-swizzled global source).
// QLEN=256: super-tile = 1 row. QLEN=128: super-tile = 2 rows as 2 strips.
// Wave wv owns 64 positions x all 64 co (4x4 MFMA tiles): per K-step
// 4 A ds_reads + 4 X ds_reads feed 16 MFMAs.
template<int QLEN>
__global__ __launch_bounds__(256, 1) void conv6(const unsigned short* __restrict__ X,
                                                unsigned short* __restrict__ Y,
                                                const unsigned short* __restrict__ A2,
                                                const float* __restrict__ bias,
                                                const unsigned short* __restrict__ ZP) {
  constexpr int SEGROWS = 256 / QLEN;              // 1 or 2 strips
  constexpr int NG      = (256 + 8 * SEGROWS) / 8; // 33 or 34 groups of 1KB
  __shared__ __align__(16) char lds[73728 + 2 * 34816];
  char* Alds  = lds;
  char* xbuf0 = lds + 73728;
  char* xbuf1 = lds + 73728 + 34816;

  const int t = threadIdx.x;
  const int lane = t & 63, wv = t >> 6;
  const int llo = lane & 15, lhi = lane >> 4;

  // ---- A -> LDS: 72 x 1KB groups, 18 per wave ----
#pragma unroll
  for (int i = 0; i < 18; ++i) {
    int m = wv + i * 4;
    gload_lds16(A2 + (size_t)m * 512 + lane * 8, Alds + m * 1024);
  }

  // stage super-tile u into dst
  auto stageX = [&](char* dst, int u) {
#pragma unroll
    for (int i = 0; i < 9; ++i) {
      int gl = wv + i * 4;
      if (gl < NG) {
        int strip = (SEGROWS == 2 && gl >= 17) ? 1 : 0;
        int gg = gl - strip * 17;
        int r = gg * 8 + (lane >> 3);            // row within strip
        int slot = lane & 7;
        int chunk = slot ^ (r & 7);
        int q = r - 4;
        int rowId = (SEGROWS == 1) ? u : u * 2 + strip;
        const void* src = ((unsigned)q < (unsigned)QLEN)
            ? (const void*)(X + (size_t)rowId * (QLEN * 64) + (size_t)q * 64 + chunk * 8)
            : (const void*)(ZP + slot * 8);
        gload_lds16(src, dst + strip * 17408 + gg * 1024);
      }
    }
  };

  float4 bv[4];
#pragma unroll
  for (int j = 0; j < 4; ++j) bv[j] = *(const float4*)(bias + j * 16 + lhi * 4);

  const int stripoff = (SEGROWS == 1) ? 0 : (wv >> 1) * 17408;
  const int posbase  = (SEGROWS == 1) ? wv * 64 : (wv & 1) * 64;

  const int u0 = blockIdx.x * 8;
  stageX(xbuf0, u0);
  __syncthreads();

  for (int tt = 0; tt < 8; ++tt) {
    const int u = u0 + tt;
    char* cur = (tt & 1) ? xbuf1 : xbuf0;
    char* nxt = (tt & 1) ? xbuf0 : xbuf1;
    if (tt < 7) stageX(nxt, u + 1);              // issue BEFORE compute

    const char* xb = cur + stripoff;
    f32x4 acc[4][4];
#pragma unroll
    for (int i = 0; i < 4; ++i)
#pragma unroll
      for (int j = 0; j < 4; ++j) { f32x4 z = {0.f,0.f,0.f,0.f}; acc[i][j] = z; }

#pragma unroll
    for (int step = 0; step < 18; ++step) {
      const int kk = step >> 1;
      const int cg = (step & 1) * 4 + lhi;
      short8_t a[4], f[4];
#pragma unroll
      for (int j = 0; j < 4; ++j)
        a[j] = *(const short8_t*)(Alds + step * 4096 + lhi * 1024 + j * 256 + llo * 16);
#pragma unroll
      for (int i = 0; i < 4; ++i) {
        int r = posbase + i * 16 + llo + kk;
        f[i] = *(const short8_t*)(xb + r * 128 + ((cg ^ (r & 7)) << 4));
      }
#pragma unroll
      for (int i = 0; i < 4; ++i)
#pragma unroll
        for (int j = 0; j < 4; ++j)
          acc[i][j] = __builtin_amdgcn_mfma_f32_16x16x32_bf16(a[j], f[i], acc[i][j], 0, 0, 0);
    }

    // epilogue: +bias, pack 4 consecutive co, 8B stores
    const int outRow = (SEGROWS == 1) ? u : u * 2 + (wv >> 1);
    const size_t rowbase = (size_t)outRow * (QLEN * 64);
#pragma unroll
    for (int j = 0; j < 4; ++j) {
#pragma unroll
      for (int i = 0; i < 4; ++i) {
        const int q = posbase + i * 16 + llo;
        float v0 = acc[i][j][0] + bv[j].x;
        float v1 = acc[i][j][1] + bv[j].y;
        float v2 = acc[i][j][2] + bv[j].z;
        float v3 = acc[i][j][3] + bv[j].w;
        unsigned lo, hi;
        asm("v_cvt_pk_bf16_f32 %0, %1, %2" : "=v"(lo) : "v"(v0), "v"(v1));
        asm("v_cvt_pk_bf16_f32 %0, %1, %2" : "=v"(hi) : "v"(v2), "v"(v3));
        uint2 ov; ov.x = lo; ov.y = hi;
        *(uint2*)(Y + rowbase + (size_t)q * 64 + j * 16 + lhi * 4) = ov;
      }
    }
    __syncthreads();
  }
}

// ===== scan along OUTER dim P of [b][P][Q][ci], 4 ci/thread, depth-8 =====
// TRANS=1: write result transposed to [b][Q][P][ci] (outT) instead of in-place.
template<int PLEN, int QLEN, int REV, int TRANS>
__global__ __launch_bounds__(128) void scan_o4(unsigned short* __restrict__ conv,
                                               const unsigned short* __restrict__ prev,
                                               unsigned short* __restrict__ outT) {
  int idx = blockIdx.x * 128 + threadIdx.x;     // B * QLEN * 16
  int cq = idx & 15;
  int q  = (idx >> 4) % QLEN;
  int b  = idx / (16 * QLEN);
  const ptrdiff_t dp = (REV ? -1 : 1) * (ptrdiff_t)(QLEN * 64);
  const int p0 = REV ? PLEN - 1 : 0;
  size_t off = ((size_t)(b * PLEN + p0) * QLEN + q) * 64 + cq * 4;
  size_t offT = 0; ptrdiff_t dpT = 0;
  if (TRANS) {
    offT = ((size_t)(b * QLEN + q) * PLEN + p0) * 64 + cq * 4;
    dpT = (REV ? -1 : 1) * (ptrdiff_t)64;
  }
  uint2 pv = *(const uint2*)(prev + off);
  if (TRANS) *(uint2*)(outT + offT) = pv; else *(uint2*)(conv + off) = pv;
  float y0 = bf2f((unsigned short)pv.x), y1 = bf2f((unsigned short)(pv.x >> 16));
  float y2 = bf2f((unsigned short)pv.y), y3 = bf2f((unsigned short)(pv.y >> 16));
  uint2 c[8];
#pragma unroll
  for (int j = 0; j < 8; ++j) c[j] = *(const uint2*)(conv + off + (ptrdiff_t)(j + 1) * dp);
  for (int base = 1; base < PLEN; base += 8) {
#pragma unroll
    for (int j = 0; j < 8; ++j) {
      int s = base + j;
      if (s < PLEN) {
        off += dp;
        if (TRANS) offT += dpT;
        y0 = fmaxf(bf2f((unsigned short)c[j].x) + y0, 0.f);
        y1 = fmaxf(bf2f((unsigned short)(c[j].x >> 16)) + y1, 0.f);
        y2 = fmaxf(bf2f((unsigned short)c[j].y) + y2, 0.f);
        y3 = fmaxf(bf2f((unsigned short)(c[j].y >> 16)) + y3, 0.f);
        uint2 ov;
        ov.x = (unsigned)f2bf(y0) | ((unsigned)f2bf(y1) << 16);
        ov.y = (unsigned)f2bf(y2) | ((unsigned)f2bf(y3) << 16);
        if (TRANS) *(uint2*)(outT + offT) = ov; else *(uint2*)(conv + off) = ov;
        if (s + 8 < PLEN) c[j] = *(const uint2*)(conv + off + 8 * dp);
      }
    }
  }
}

extern "C" void kernel_launch(void* const* d_in, const int* in_sizes, int n_in,
                              void* d_out, int out_size, void* d_ws, size_t ws_size,
                              hipStream_t stream) {
  const float* x    = (const float*)d_in[0];
  const float* w_ud = (const float*)d_in[1];
  const float* b_ud = (const float*)d_in[2];
  const float* w_du = (const float*)d_in[3];
  const float* b_du = (const float*)d_in[4];
  const float* w_lr = (const float*)d_in[5];
  const float* b_lr = (const float*)d_in[6];
  const float* w_rl = (const float*)d_in[7];
  const float* b_rl = (const float*)d_in[8];

  // ws: A[0,64M) Bb[64M,128M) Cc[128M,192M) A2 @192M, zeropage @192M+1M
  unsigned short* A  = (unsigned short*)d_ws;
  unsigned short* Bb = (unsigned short*)((char*)d_ws + 67108864);
  unsigned short* Cc = (unsigned short*)((char*)d_ws + 134217728);
  unsigned short* A2 = (unsigned short*)((char*)d_ws + 201326592);
  unsigned short* ZP = (unsigned short*)((char*)d_ws + 202375168);
  unsigned short* A2_ud = A2 + 0 * (C_ * KDIM_);
  unsigned short* A2_du = A2 + 1 * (C_ * KDIM_);
  unsigned short* A2_lr = A2 + 2 * (C_ * KDIM_);
  unsigned short* A2_rl = A2 + 3 * (C_ * KDIM_);

  // NOTE: no hipMemsetAsync — ZP is zeroed inside prep_w_all (the 1KB fill
  // dispatch cost ~75us per replay per R9/R10 rocprof).
  dim3 pg((C_ * KDIM_ + 255) / 256, 4);
  prep_w_all<<<pg, 256, 0, stream>>>(w_ud, w_du, w_lr, w_rl, A2, (float*)ZP);

  transpose_in<<<dim3(4, H_, B_), 256, 0, stream>>>(x, A);

  // sweep 1 (ud): conv along W on [b][h][w][ci]; scan fwd along h
  conv6<W_><<<256, 256, 0, stream>>>(A, Bb, A2_ud, b_ud, ZP);
  scan_o4<H_, W_, 0, 0><<<512, 128, 0, stream>>>(Bb, A, nullptr);

  // sweep 2 (du): conv along W; scan rev along h, WRITE TRANSPOSED -> [b][w][h][ci]
  conv6<W_><<<256, 256, 0, stream>>>(Bb, Cc, A2_du, b_du, ZP);
  scan_o4<H_, W_, 1, 1><<<512, 128, 0, stream>>>(Cc, Bb, A);

  // sweep 3 (lr): conv along H (inner dim of flipped layout); scan fwd along w
  conv6<H_><<<256, 256, 0, stream>>>(A, Bb, A2_lr, b_lr, ZP);
  scan_o4<W_, H_, 0, 0><<<256, 128, 0, stream>>>(Bb, A, nullptr);

  // sweep 4 (rl): conv along H; scan rev along w
  conv6<H_><<<256, 256, 0, stream>>>(Bb, Cc, A2_rl, b_rl, ZP);
  scan_o4<W_, H_, 1, 0><<<256, 128, 0, stream>>>(Cc, Bb, nullptr);

  transpose_out_wh<<<dim3(4, H_, B_), 256, 0, stream>>>(Cc, (float*)d_out);
}